// Round 1
// baseline (32.551 us; speedup 1.0000x reference)
//
#include <hip/hip_runtime.h>

// Lucas-Kanade optical flow, fused single kernel.
// Input:  image_prev, image_next  (1,1,2048,2048) fp32
// Output: (1,2,2048,2048) fp32  -> u at [0:H*W], v at [H*W:2*H*W]

#define IMG_H 2048
#define IMG_W 2048
#define TILE  32

// Block FMA contraction so we match the numpy reference's separately-rounded
// multiply->add sequences (det/numerators cancel catastrophically where |u| is
// largest; fused vs unfused there can exceed the absmax threshold).
__device__ __forceinline__ float mulnf(float a, float b) {
    float t = a * b;
    asm("" : "+v"(t));
    return t;
}

__global__ __launch_bounds__(256)
void lk_flow_kernel(const float* __restrict__ prev,
                    const float* __restrict__ next,
                    float* __restrict__ out) {
    // res tiles with 1-halo on each side: (TILE+2)^2 valid, stride padded to +4
    __shared__ float srx[TILE + 2][TILE + 4];
    __shared__ float sry[TILE + 2][TILE + 4];
    __shared__ float srt[TILE + 2][TILE + 4];

    const int r0 = blockIdx.y * TILE;
    const int c0 = blockIdx.x * TILE;
    const int tid = threadIdx.y * 32 + threadIdx.x;

    // Phase A: compute resx/resy/resdt on the (TILE+2)x(TILE+2) halo tile.
    // res(a,b) valid only for 0<=a<H, 0<=b<W (box3 zero-pads outside).
    for (int idx = tid; idx < (TILE + 2) * (TILE + 2); idx += 256) {
        const int lr = idx / (TILE + 2);
        const int lc = idx - lr * (TILE + 2);
        const int a = r0 - 1 + lr;
        const int b = c0 - 1 + lc;
        float rx = 0.0f, ry = 0.0f, rt = 0.0f;
        if (a >= 0 && a < IMG_H && b >= 0 && b < IMG_W) {
            // reflect pad (after only): p[H] = x[H-2], p[:,W] = x[:,W-2]
            const int a1 = (a + 1 == IMG_H) ? (IMG_H - 2) : (a + 1);
            const int b1 = (b + 1 == IMG_W) ? (IMG_W - 2) : (b + 1);
            const float p00 = prev[a  * IMG_W + b ];
            const float p01 = prev[a  * IMG_W + b1];
            const float p10 = prev[a1 * IMG_W + b ];
            const float p11 = prev[a1 * IMG_W + b1];
            const float q00 = next[a  * IMG_W + b ];
            const float q01 = next[a  * IMG_W + b1];
            const float q10 = next[a1 * IMG_W + b ];
            const float q11 = next[a1 * IMG_W + b1];
            // exact left-to-right order as the reference elementwise exprs
            const float gxp = -p00 + p01 - p10 + p11;
            const float gxq = -q00 + q01 - q10 + q11;
            const float gyp = -p00 - p01 + p10 + p11;
            const float gyq = -q00 - q01 + q10 + q11;
            const float gsp =  p00 + p01 + p10 + p11;
            const float gsq =  q00 + q01 + q10 + q11;
            rx = 0.5f * (gxp + gxq);
            ry = 0.5f * (gyp + gyq);
            rt = 0.5f * (-gsp + gsq);
        }
        srx[lr][lc] = rx;
        sry[lr][lc] = ry;
        srt[lr][lc] = rt;
    }
    __syncthreads();

    // Phase B: 3x3 box sums of products + 2x2 solve. Each thread does 4 rows.
    const int tx = threadIdx.x;
    #pragma unroll
    for (int s = 0; s < 4; ++s) {
        const int oy = threadIdx.y + s * 8;
        const int i = r0 + oy;
        const int j = c0 + tx;
        float Sxx = 0.0f, Syy = 0.0f, Sxy = 0.0f, Sxt = 0.0f, Syt = 0.0f;
        // accumulate in the reference's box3 order: (dr,dc) row-major
        #pragma unroll
        for (int dr = 0; dr < 3; ++dr) {
            #pragma unroll
            for (int dc = 0; dc < 3; ++dc) {
                const float rx = srx[oy + dr][tx + dc];
                const float ry = sry[oy + dr][tx + dc];
                const float rt = srt[oy + dr][tx + dc];
                Sxx += mulnf(rx, rx);
                Syy += mulnf(ry, ry);
                Sxy += mulnf(rx, ry);
                Sxt += mulnf(rt, rx);
                Syt += mulnf(rt, ry);
            }
        }
        const float t1 = mulnf(Sxx, Syy);
        const float t2 = mulnf(Sxy, Sxy);
        const float det = t1 - t2;
        float u = 0.0f, v = 0.0f;
        if (det != 0.0f) {
            const float n1 = mulnf(Syy, Sxt) - mulnf(Sxy, Syt);
            const float n2 = mulnf(Sxx, Syt) - mulnf(Sxy, Sxt);
            u = n1 / det;   // IEEE fp32 divide (no fast-math)
            v = n2 / det;
        }
        // reference zeroes row 0 and col 0
        if (i == 0 || j == 0) { u = 0.0f; v = 0.0f; }
        out[i * IMG_W + j] = u;
        out[IMG_H * IMG_W + i * IMG_W + j] = v;
    }
}

extern "C" void kernel_launch(void* const* d_in, const int* in_sizes, int n_in,
                              void* d_out, int out_size, void* d_ws, size_t ws_size,
                              hipStream_t stream) {
    const float* prev = (const float*)d_in[0];
    const float* next = (const float*)d_in[1];
    float* out = (float*)d_out;
    dim3 grid(IMG_W / TILE, IMG_H / TILE);  // 64 x 64
    dim3 block(32, 8);
    lk_flow_kernel<<<grid, block, 0, stream>>>(prev, next, out);
}